// Round 9
// baseline (31.579 us; speedup 1.0000x reference)
//
#include <hip/hip_runtime.h>

// EmbeddingBag(mean): B=1024, S=256, W=16, EMB=50, vocab=256.
// Round 9: bf16 table (halve DS bytes) on r6's exact winning structure.
//  - Model (r4-r8 evidence): branchy exec-mask gather pays DS bank cycles
//    only for ACTIVE lanes -> DS data cost ~ sum(len) (~8.5 rows/bag), which
//    is why sorts (r5/r7) and flat predication (r8) couldn't beat r6.
//    fp32 DS data ~464MB (~9us); bf16 -> 285MB (~5.5us). VALU unpack ~6.5us
//    aggregate stays below DS+HBM.
//  - r4's bf16 loss was LB(512,8)'s VGPR=64 cap serializing loads; now
//    LB(512,6) -> VGPR<=85, 3 blocks/CU = 24 waves.
//  - Geometry: 8 lanes/bag (t=tid&7, no div), 64 bags/pass, CHUNK=256,
//    4 passes exact -> zero inactive lanes, zero tail.
//  - Keeps r6: lenbuf staging, next-pass chars prefetch, per-row branch
//    nest, contiguous chunks, coalesced float2 stores.
//  - Row stride 72 bf16 = 144B = 36 dwords (gcd(36,32)=4 -> 8 distinct
//    bank-start classes, r4-proven).

constexpr int EMB     = 50;
constexpr int RSTRIDE = 72;                  // bf16 elems per row (144 B)
constexpr int TBL_DW  = 256 * (RSTRIDE/2);   // 9216 dwords = 36 KB
constexpr int NBAGS   = 1024 * 256;          // 262144
constexpr int BLOCK   = 512;
constexpr int BPP     = BLOCK / 8;           // 64 bags per pass
constexpr int CHUNK   = 256;                 // bags per block
constexpr int NPASS   = CHUNK / BPP;         // 4, exact
constexpr int BLOCKS  = NBAGS / CHUNK;       // 1024, exact

__device__ __forceinline__ unsigned bf16_rne(float f) {
    unsigned u = __float_as_uint(f);
    u += 0x7fffu + ((u >> 16) & 1u);
    return u >> 16;
}

__global__ __launch_bounds__(BLOCK, 6) void embag_bf16r9_kernel(
    const int*   __restrict__ chars,     // [NBAGS, W=16]
    const int*   __restrict__ lengths,   // [NBAGS]
    const float* __restrict__ table,     // [256, EMB]
    float*       __restrict__ out)       // [NBAGS, EMB]
{
    __shared__ unsigned lds_u[TBL_DW];
    __shared__ int      lenbuf[CHUNK];
    __shared__ float    invl[17];

    const int base = blockIdx.x * CHUNK;

    // Stage table as packed bf16 pairs; cols 50..71 zero. Pair never
    // straddles a row (RSTRIDE even).
    for (int i = threadIdx.x; i < TBL_DW; i += BLOCK) {
        const int r = i / 36;
        const int c = 2 * i - r * RSTRIDE;
        const float f0 = (c     < EMB) ? table[r * EMB + c]     : 0.f;
        const float f1 = (c + 1 < EMB) ? table[r * EMB + c + 1] : 0.f;
        lds_u[i] = bf16_rne(f0) | (bf16_rne(f1) << 16);
    }
    if (threadIdx.x < CHUNK / 4)
        reinterpret_cast<int4*>(lenbuf)[threadIdx.x] =
            reinterpret_cast<const int4*>(lengths + base)[threadIdx.x];
    if (threadIdx.x < 17)
        invl[threadIdx.x] = threadIdx.x ? 1.0f / (float)threadIdx.x : 0.0f;
    __syncthreads();

    const int lb = threadIdx.x >> 3;           // bag slot in pass, 0..63
    const int t  = threadIdx.x & 7;            // 16B slot within row
    const char* ldsb = reinterpret_cast<const char*>(lds_u);
    const unsigned lanebyte = (unsigned)t * 16u;

    // Prologue: prefetch pass-0 chars.
    int idx = lb;
    const int4* cp0 = reinterpret_cast<const int4*>(chars + (size_t)(base + idx) * 16);
    int4 c0 = cp0[0], c1 = cp0[1], c2 = cp0[2], c3 = cp0[3];

    for (int p = 0; p < NPASS; ++p) {
        // Prefetch next pass's chars (clamped on last pass; retires under gathers).
        const int idxn = (p < NPASS - 1) ? idx + BPP : idx;
        const int4* cpn =
            reinterpret_cast<const int4*>(chars + (size_t)(base + idxn) * 16);
        const int4 n0 = cpn[0], n1 = cpn[1], n2 = cpn[2], n3 = cpn[3];

        const int len = lenbuf[idx];

        float a0 = 0.f, a1 = 0.f, a2 = 0.f, a3 = 0.f;
        float a4 = 0.f, a5 = 0.f, a6 = 0.f, a7 = 0.f;

        // One row: ds_read_b128 of this lane's 8 bf16, unpack (lshl/and) + add.
        #define G(eidx)                                                       \
            {                                                                 \
                const uint4 v = *reinterpret_cast<const uint4*>(              \
                    ldsb + (unsigned)(eidx) * 144u + lanebyte);               \
                a0 += __uint_as_float(v.x << 16);                             \
                a1 += __uint_as_float(v.x & 0xffff0000u);                     \
                a2 += __uint_as_float(v.y << 16);                             \
                a3 += __uint_as_float(v.y & 0xffff0000u);                     \
                a4 += __uint_as_float(v.z << 16);                             \
                a5 += __uint_as_float(v.z & 0xffff0000u);                     \
                a6 += __uint_as_float(v.w << 16);                             \
                a7 += __uint_as_float(v.w & 0xffff0000u);                     \
            }

        G(c0.x)
        if (len > 1)  { G(c0.y)
        if (len > 2)  { G(c0.z)
        if (len > 3)  { G(c0.w)
        if (len > 4)  { G(c1.x)
        if (len > 5)  { G(c1.y)
        if (len > 6)  { G(c1.z)
        if (len > 7)  { G(c1.w)
        if (len > 8)  { G(c2.x)
        if (len > 9)  { G(c2.y)
        if (len > 10) { G(c2.z)
        if (len > 11) { G(c2.w)
        if (len > 12) { G(c3.x)
        if (len > 13) { G(c3.y)
        if (len > 14) { G(c3.z)
        if (len > 15) { G(c3.w) }}}}}}}}}}}}}}}
        #undef G

        const float inv = invl[len];

        // Lane t owns out elems [8t, 8t+8): t<6 all 8, t==6 only 48..49.
        float* ob = out + (size_t)(base + idx) * EMB + (unsigned)t * 8u;
        if (t < 6) {
            reinterpret_cast<float2*>(ob)[0] = make_float2(a0 * inv, a1 * inv);
            reinterpret_cast<float2*>(ob)[1] = make_float2(a2 * inv, a3 * inv);
            reinterpret_cast<float2*>(ob)[2] = make_float2(a4 * inv, a5 * inv);
            reinterpret_cast<float2*>(ob)[3] = make_float2(a6 * inv, a7 * inv);
        } else if (t == 6) {
            reinterpret_cast<float2*>(ob)[0] = make_float2(a0 * inv, a1 * inv);
        }

        c0 = n0; c1 = n1; c2 = n2; c3 = n3;
        idx += BPP;
    }
}

extern "C" void kernel_launch(void* const* d_in, const int* in_sizes, int n_in,
                              void* d_out, int out_size, void* d_ws, size_t ws_size,
                              hipStream_t stream) {
    const int*   chars   = (const int*)d_in[0];   // [B,S,W] int32
    const int*   lengths = (const int*)d_in[1];   // [B,S]   int32
    const float* table   = (const float*)d_in[2]; // [256,50] f32
    float*       out     = (float*)d_out;         // [B,S,50] f32

    embag_bf16r9_kernel<<<dim3(BLOCKS), dim3(BLOCK), 0, stream>>>(
        chars, lengths, table, out);
}

// Round 10
// 30.027 us; speedup vs baseline: 1.0517x; 1.0517x over previous
//
#include <hip/hip_runtime.h>

// EmbeddingBag(mean) as MFMA GEMM: out = counts(A) @ table(B), scaled by 1/len.
// B=1024,S=256 -> 262144 bags; W=16; EMB=50; vocab=256.
//
// Per 16-bag tile (one wave, no block barriers in main loop):
//   A: 16x256 u16 counts in wave-private LDS (frag-ordered), built by
//      zero + packed ds_add_u32 scatter (duplicates accumulate exactly).
//   B: table as bf16 fragments, built once in LDS, then held in 128 VGPRs.
//   C = sum_v A[bag,v]*T[v,e] via 4 N-tiles x 8 K-steps of
//      mfma_f32_16x16x32_bf16; epilogue scales by 1/len (f32).
// Layout safety: A/B k-order uncertainty cancels (same v->(kslice,elem) map
// used for both); C/D layout is HW-verified: col=lane&15, row=(lane>>4)*4+reg.
// Counts 0..16 are exact in bf16; table bf16-RNE absmax ~0.0156 (r4/r9).

constexpr int EMB    = 50;
constexpr int NBAGS  = 1024 * 256;       // 262144
constexpr int BLOCK  = 256;              // 4 waves
constexpr int WAVES  = 4;
constexpr int TPW    = 8;                // tiles per wave
constexpr int TILES_PER_BLOCK = WAVES * TPW;          // 32 tiles = 512 bags
constexpr int BLOCKS = NBAGS / (TILES_PER_BLOCK * 16); // 512, exact

typedef __attribute__((ext_vector_type(8))) short short8;
typedef __attribute__((ext_vector_type(4))) float f32x4;

__device__ __forceinline__ unsigned bf16_rne(float f) {
    unsigned u = __float_as_uint(f);
    u += 0x7fffu + ((u >> 16) & 1u);
    return u >> 16;
}
// two u16 counts -> packed pair of bf16 (exact: counts <= 16 need 5 sig bits)
__device__ __forceinline__ unsigned cnt2bf(unsigned w) {
    const float f0 = (float)(w & 0xffffu);
    const float f1 = (float)(w >> 16);
    return (__float_as_uint(f0) >> 16) | (__float_as_uint(f1) & 0xffff0000u);
}

__global__ __launch_bounds__(BLOCK, 2) void embag_mfma_kernel(
    const int*   __restrict__ chars,     // [NBAGS,16]
    const int*   __restrict__ lengths,   // [NBAGS]
    const float* __restrict__ table,     // [256,50]
    float*       __restrict__ out)       // [NBAGS,50]
{
    // LDS: B-frags 32KB | per-wave A count buffers 4x8KB | len/inv 4KB = 68KB
    __shared__ __align__(16) unsigned bfr[8192];
    __shared__ __align__(16) unsigned abuf[WAVES][2048];
    __shared__ float invbuf[512];
    __shared__ int   lenbuf[512];

    const int base = blockIdx.x * (TILES_PER_BLOCK * 16);  // first bag

    // ---- stage lengths + inverse
    for (int i = threadIdx.x; i < 512; i += BLOCK) {
        const int L = lengths[base + i];
        lenbuf[i] = L;
        invbuf[i] = 1.0f / (float)L;
    }
    // ---- build B fragments: word w -> (t,K,lane,dw); elems e=2dw,2dw+1.
    //      v = K*32 + (lane>>4)*8 + e ; col = t*16 + (lane&15)
    for (int w = threadIdx.x; w < 8192; w += BLOCK) {
        const int dw = w & 3, lane = (w >> 2) & 63, K = (w >> 8) & 7, t = w >> 11;
        const int col = t * 16 + (lane & 15);
        const int v0  = K * 32 + ((lane >> 4) << 3) + dw * 2;
        const float f0 = (col < EMB) ? table[v0 * EMB + col]       : 0.f;
        const float f1 = (col < EMB) ? table[(v0 + 1) * EMB + col] : 0.f;
        bfr[w] = bf16_rne(f0) | (bf16_rne(f1) << 16);
    }
    __syncthreads();

    const int lane = threadIdx.x & 63;
    const int wid  = threadIdx.x >> 6;
    const int row  = lane & 15;          // A-row (bag-in-tile) / C-col
    const int wg   = lane >> 4;          // k-slice group / C-row group

    // ---- B fragments to registers (held for the whole kernel)
    short8 bf[4][8];
    #pragma unroll
    for (int t = 0; t < 4; ++t)
        #pragma unroll
        for (int K = 0; K < 8; ++K)
            bf[t][K] = __builtin_bit_cast(short8,
                reinterpret_cast<const uint4*>(bfr)[(t * 8 + K) * 64 + lane]);

    unsigned* aw  = abuf[wid];
    uint4*    aw4 = reinterpret_cast<uint4*>(aw);

    // prologue: prefetch tile 0's chars (lane covers bag row, w-group wg)
    const int tl0 = wid * TPW;
    int4 ccur = *reinterpret_cast<const int4*>(
        chars + (size_t)(base + tl0 * 16 + row) * 16 + wg * 4);

    for (int it = 0; it < TPW; ++it) {
        const int tloc  = wid * TPW + it;
        const int tbase = base + tloc * 16;

        // prefetch next tile's chars (clamped on last iter)
        const int pbase = (it + 1 < TPW) ? tbase + 16 : tbase;
        const int4 cnext = *reinterpret_cast<const int4*>(
            chars + (size_t)(pbase + row) * 16 + wg * 4);

        const int len = lenbuf[tloc * 16 + row];

        // ---- zero A (8 KB, dense, conflict-free)
        const uint4 z = make_uint4(0u, 0u, 0u, 0u);
        #pragma unroll
        for (int i = 0; i < 8; ++i) aw4[i * 64 + lane] = z;

        // ---- scatter counts: w = wg*4+i ; packed u16 += 1 (no overflow)
        const int cs[4] = {ccur.x, ccur.y, ccur.z, ccur.w};
        #pragma unroll
        for (int i = 0; i < 4; ++i) {
            if (wg * 4 + i < len) {
                const unsigned c = (unsigned)cs[i];
                const unsigned word = ((c >> 5) << 8)
                    + ((unsigned)(row + (((c >> 3) & 3u) << 4)) << 2)
                    + ((c & 7u) >> 1);
                atomicAdd(&aw[word], 1u << ((c & 1u) * 16));
            }
        }

        // ---- read A fragments, convert counts -> bf16
        short8 af[8];
        #pragma unroll
        for (int K = 0; K < 8; ++K) {
            const uint4 u = aw4[K * 64 + lane];
            uint4 p;
            p.x = cnt2bf(u.x); p.y = cnt2bf(u.y);
            p.z = cnt2bf(u.z); p.w = cnt2bf(u.w);
            af[K] = __builtin_bit_cast(short8, p);
        }

        // ---- inv for this lane's 4 C-rows
        float inv4[4];
        #pragma unroll
        for (int j = 0; j < 4; ++j) inv4[j] = invbuf[tloc * 16 + wg * 4 + j];

        // ---- 4 N-tiles of MFMA + epilogue
        #pragma unroll
        for (int t = 0; t < 4; ++t) {
            f32x4 acc = {0.f, 0.f, 0.f, 0.f};
            #pragma unroll
            for (int K = 0; K < 8; ++K)
                acc = __builtin_amdgcn_mfma_f32_16x16x32_bf16(
                    af[K], bf[t][K], acc, 0, 0, 0);
            const int col = t * 16 + row;            // C col = lane&15
            if (col < EMB) {
                #pragma unroll
                for (int j = 0; j < 4; ++j)          // C row = wg*4 + j
                    out[(size_t)(tbase + wg * 4 + j) * EMB + col] =
                        acc[j] * inv4[j];
            }
        }

        ccur = cnext;
    }
}

extern "C" void kernel_launch(void* const* d_in, const int* in_sizes, int n_in,
                              void* d_out, int out_size, void* d_ws, size_t ws_size,
                              hipStream_t stream) {
    const int*   chars   = (const int*)d_in[0];   // [B,S,W] int32
    const int*   lengths = (const int*)d_in[1];   // [B,S]   int32
    const float* table   = (const float*)d_in[2]; // [256,50] f32
    float*       out     = (float*)d_out;         // [B,S,50] f32

    embag_mfma_kernel<<<dim3(BLOCKS), dim3(BLOCK), 0, stream>>>(
        chars, lengths, table, out);
}